// Round 1
// baseline (15.649 us; speedup 1.0000x reference)
//
#include <hip/hip_runtime.h>

// cross_attention_89653147337302
//
// Algebraic collapse: softmax(.., axis=-1) followed by mean(.., axis=-1)
// gives exactly 1/n per row (softmax rows sum to 1). softmax of that
// constant vector gives 1/n again, so weight = 1 + 1/4096 everywhere.
// The whole op reduces to out = concat(xv, xt) * (1 + 2^-12).
//
// Pure memory-bound elementwise scale: 67 MB total traffic -> ~11 us floor.

__global__ __launch_bounds__(256) void ca_scale_kernel(
    const float4* __restrict__ xv,
    const float4* __restrict__ xt,
    float4* __restrict__ out,
    int n4)  // number of float4 elements per input
{
    const float w = 1.0f + 1.0f / 4096.0f;  // 1.000244140625, exact in fp32
    int i = blockIdx.x * blockDim.x + threadIdx.x;
    const int stride = gridDim.x * blockDim.x;
    for (; i < n4; i += stride) {
        float4 a = xv[i];
        a.x *= w; a.y *= w; a.z *= w; a.w *= w;
        out[i] = a;
        float4 b = xt[i];
        b.x *= w; b.y *= w; b.z *= w; b.w *= w;
        out[n4 + i] = b;
    }
}

extern "C" void kernel_launch(void* const* d_in, const int* in_sizes, int n_in,
                              void* d_out, int out_size, void* d_ws, size_t ws_size,
                              hipStream_t stream) {
    const float* xv = (const float*)d_in[0];
    const float* xt = (const float*)d_in[1];
    float* out = (float*)d_out;

    const int n = in_sizes[0];      // 16*64*64*64 = 4194304 floats per input
    const int n4 = n >> 2;          // 1048576 float4 per input

    const int block = 256;
    const int grid = 2048;          // grid-stride; ~2 iters/thread

    ca_scale_kernel<<<grid, block, 0, stream>>>(
        (const float4*)xv, (const float4*)xt, (float4*)out, n4);
}